// Round 24
// baseline (302.145 us; speedup 1.0000x reference)
//
#include <hip/hip_runtime.h>

// GNNML3 R24: R23 (287.1us) with the node epilogue FUSED into fusedM.
// Waves 0/1 apply bias+relu to their in-register conv outputs and write
// xnext/xbnext directly (no acc round-trip); wave 2 computes the gate
// (x@U+ub)*(x@V+vb) with U/V staged in LDS. FINAL (layer 3) reduces the
// fc2 dot via per-wave shfl trees into fixed-order LDS partials (determin-
// istic), then writes out. Layer 1 unchanged. Kills 2 epilogue launches +
// 2x(6.4MB acc write + read).

constexpr int K  = 10;   // spectral supports
constexpr int C1 = 32;   // conv out
constexpr int C2 = 16;   // gate out
constexpr int CC = 48;   // concat width
constexpr int KD = 480;  // kd = c*10 + k
constexpr int KSTEPS = 15;
constexpr int HROW = 488;              // LDS H row stride (padded, bank-friendly)
constexpr int RTILE = 4096;            // radix items per block
constexpr int RS_WAVES  = 16;          // waves per rscatter block (1024 thr)
constexpr int RS_THREADS = RS_WAVES * 64;
constexpr int RS_ROUNDS = RTILE / RS_THREADS;        // 4 rounds per wave

typedef short bf16x8 __attribute__((ext_vector_type(8)));
typedef float f32x4  __attribute__((ext_vector_type(4)));
typedef unsigned int uintx4 __attribute__((ext_vector_type(4)));

static __device__ __forceinline__ unsigned short f2bf(float f) {
    unsigned int u = __float_as_uint(f);
    return (unsigned short)((u + 0x7FFFu + ((u >> 16) & 1u)) >> 16);
}
static __device__ __forceinline__ float bf2f(unsigned short h) {
    return __uint_as_float(((unsigned int)h) << 16);
}
static __device__ __forceinline__ unsigned int pk2(float a, float b) {
    return (unsigned int)f2bf(a) | ((unsigned int)f2bf(b) << 16);
}

// ---------------- build: keys + idx + packed 32B records ----------------
__global__ __launch_bounds__(256)
void build_kernel(const float* __restrict__ ea, const int* __restrict__ src,
                  const int* __restrict__ dst, unsigned short* __restrict__ rec,
                  unsigned short* __restrict__ keys0, unsigned int* __restrict__ idx0,
                  int E) {
    int e = blockIdx.x * 256 + threadIdx.x;
    if (e >= E) return;
    keys0[e] = (unsigned short)dst[e];
    idx0[e] = (unsigned int)e;
    const float2* ep = (const float2*)(ea + (size_t)e * K);
    float2 a0 = ep[0], a1 = ep[1], a2 = ep[2], a3 = ep[3], a4 = ep[4];
    uint4 r0, r1;
    r0.x = pk2(a0.x, a0.y); r0.y = pk2(a1.x, a1.y);
    r0.z = pk2(a2.x, a2.y); r0.w = pk2(a3.x, a3.y);
    r1.x = pk2(a4.x, a4.y); r1.y = (unsigned int)src[e];
    r1.z = 0u; r1.w = 0u;
    uint4* rp = (uint4*)(rec + (size_t)e * 16);
    rp[0] = r0; rp[1] = r1;
}

// ---------------- radix machinery (no global atomics) ----------------
template<int SHIFT>
__global__ __launch_bounds__(256)
void rcount_kernel(const unsigned short* __restrict__ keys,
                   unsigned int* __restrict__ counts, int E, int NB) {
    __shared__ unsigned int h[256];
    h[threadIdx.x] = 0;
    __syncthreads();
    int end = min((blockIdx.x + 1) * RTILE, E);
    for (int i = blockIdx.x * RTILE + threadIdx.x; i < end; i += 256)
        atomicAdd(&h[(keys[i] >> SHIFT) & 255], 1);   // LDS atomic (cheap)
    __syncthreads();
    counts[(size_t)threadIdx.x * NB + blockIdx.x] = h[threadIdx.x];
}

// per-digit exclusive scan across NB blocks: grid = 256 blocks (one per digit)
__global__ __launch_bounds__(256)
void digit_scan_kernel(const unsigned int* __restrict__ counts,
                       unsigned int* __restrict__ gscan,
                       unsigned int* __restrict__ dtot, int NB) {
    __shared__ unsigned int s[256];
    int d = blockIdx.x, t = threadIdx.x;
    const unsigned int* row = counts + (size_t)d * NB;
    unsigned int* orow = gscan + (size_t)d * NB;
    unsigned int running = 0;
    for (int base = 0; base < NB; base += 256) {
        int i = base + t;
        unsigned int v = (i < NB) ? row[i] : 0u;
        s[t] = v;
        __syncthreads();
#pragma unroll
        for (int off = 1; off < 256; off <<= 1) {
            unsigned int a = (t >= off) ? s[t - off] : 0u;
            __syncthreads();
            s[t] += a;
            __syncthreads();
        }
        if (i < NB) orow[i] = running + s[t] - v;   // exclusive
        running += s[255];
        __syncthreads();
    }
    if (t == 0) dtot[d] = running;
}

// stable scatter via wave-ballot ranking. 1024 threads (16 waves), ~51KB LDS.
template<int SHIFT>
__global__ __launch_bounds__(RS_THREADS)
void rscatter_kernel(const unsigned short* __restrict__ keyIn,
                     const unsigned int* __restrict__ idxIn,
                     const unsigned int* __restrict__ gscan,
                     const unsigned int* __restrict__ dtot,
                     unsigned short* __restrict__ keyOut,
                     unsigned int* __restrict__ idxOut, int E, int NB) {
    __shared__ unsigned int hw[RS_WAVES][256];    // per-wave digit histogram
    __shared__ unsigned int wex[RS_WAVES][256];   // wave-exclusive per-digit prefix
    __shared__ unsigned int wrun[RS_WAVES][256];  // per-wave running counters
    __shared__ unsigned int dbt[256];
    __shared__ unsigned int gb[256];              // global base per digit
    int t = threadIdx.x, b = blockIdx.x;
    int w = t >> 6, lane = t & 63;
    {
        unsigned int* hwf = &hw[0][0];
        unsigned int* wrf = &wrun[0][0];
        for (int i = t; i < RS_WAVES * 256; i += RS_THREADS) { hwf[i] = 0; wrf[i] = 0; }
    }
    unsigned int dv = (t < 256) ? dtot[t] : 0u;
    if (t < 256) dbt[t] = dv;
    __syncthreads();
#pragma unroll
    for (int off = 1; off < 256; off <<= 1) {
        unsigned int a = (t >= off && t < 256) ? dbt[t - off] : 0u;
        __syncthreads();
        if (t < 256) dbt[t] += a;
        __syncthreads();
    }
    if (t < 256) gb[t] = (dbt[t] - dv) + gscan[(size_t)t * NB + b];
    // phase 1: load items (wave-major, round-major, lane-major) + wave hists
    int base = b * RTILE + w * (RTILE / RS_WAVES);
    unsigned short keys[RS_ROUNDS]; unsigned int idxs[RS_ROUNDS]; unsigned int dig[RS_ROUNDS];
#pragma unroll
    for (int r = 0; r < RS_ROUNDS; ++r) {
        int i = base + r * 64 + lane;
        if (i < E) {
            keys[r] = keyIn[i];
            idxs[r] = idxIn[i];
            dig[r] = (keys[r] >> SHIFT) & 255u;
            atomicAdd(&hw[w][dig[r]], 1u);
        } else dig[r] = 0xFFFFFFFFu;
    }
    __syncthreads();
    // phase 2: per-digit wave-exclusive prefix (thread t<256 owns digit t)
    if (t < 256) {
        unsigned int s = 0;
#pragma unroll
        for (int ww = 0; ww < RS_WAVES; ++ww) { wex[ww][t] = s; s += hw[ww][t]; }
    }
    __syncthreads();
    // phase 3: stable rank, rounds in order within wave
#pragma unroll
    for (int r = 0; r < RS_ROUNDS; ++r) {
        bool valid = dig[r] != 0xFFFFFFFFu;
        unsigned int d = valid ? dig[r] : 0u;
        unsigned long long mask = __ballot(valid);
#pragma unroll
        for (int bit = 0; bit < 8; ++bit) {
            unsigned long long bb = __ballot(valid && ((d >> bit) & 1u));
            mask &= ((d >> bit) & 1u) ? bb : ~bb;
        }
        unsigned int old = 0;
        if (valid) {
            int leader = __ffsll((long long)mask) - 1;
            if (lane == leader) {
                old = wrun[w][d];
                wrun[w][d] = old + (unsigned int)__popcll(mask);
            }
            old = __shfl(old, leader);
            unsigned int myrank = (unsigned int)__popcll(mask & ((1ull << lane) - 1ull));
            unsigned int pos = gb[d] + wex[w][d] + old + myrank;
            keyOut[pos] = keys[r];
            idxOut[pos] = idxs[r];
        }
    }
}

// permutation gather: one 32B-aligned record read per edge -> planes + src_d
__global__ __launch_bounds__(256)
void materialize_kernel(const unsigned int* __restrict__ idxS,
                        const unsigned short* __restrict__ rec,
                        unsigned short* __restrict__ ea_t,
                        int* __restrict__ src_d, int E, int Epad) {
    int r = blockIdx.x * 256 + threadIdx.x;
    if (r >= Epad) return;
    if (r < E) {
        unsigned int p = idxS[r];
        const uint4* rp = (const uint4*)(rec + (size_t)p * 16);
        uint4 r0 = rp[0], r1 = rp[1];
        src_d[r] = (int)r1.y;
        ea_t[(size_t)0 * Epad + r] = (unsigned short)r0.x;
        ea_t[(size_t)1 * Epad + r] = (unsigned short)(r0.x >> 16);
        ea_t[(size_t)2 * Epad + r] = (unsigned short)r0.y;
        ea_t[(size_t)3 * Epad + r] = (unsigned short)(r0.y >> 16);
        ea_t[(size_t)4 * Epad + r] = (unsigned short)r0.z;
        ea_t[(size_t)5 * Epad + r] = (unsigned short)(r0.z >> 16);
        ea_t[(size_t)6 * Epad + r] = (unsigned short)r0.w;
        ea_t[(size_t)7 * Epad + r] = (unsigned short)(r0.w >> 16);
        ea_t[(size_t)8 * Epad + r] = (unsigned short)r1.x;
        ea_t[(size_t)9 * Epad + r] = (unsigned short)(r1.x >> 16);
    } else {
        src_d[r] = 0;
#pragma unroll
        for (int k = 0; k < K; ++k) ea_t[(size_t)k * Epad + r] = 0;
    }
}

// rowptr[n] = lower_bound(sorted keys, n)
__global__ __launch_bounds__(256)
void rowptr_kernel(const unsigned short* __restrict__ keysS,
                   int* __restrict__ rowptr, int N, int E) {
    int n = blockIdx.x * 256 + threadIdx.x;
    if (n >= N) return;
    int lo = 0, hi = E;
    while (lo < hi) {
        int mid = (lo + hi) >> 1;
        if ((int)keysS[mid] < n) lo = mid + 1; else hi = mid;
    }
    rowptr[n] = lo;
}

// ---------------- W -> B-fragments (all three in one launch) ----------------
static __device__ __forceinline__
void wconv_entry(const float* __restrict__ W, unsigned short* __restrict__ out,
                 int li, int kdact, int cin) {
    int t = li >> 7, rem = li & 127, h = rem >> 6, l = rem & 63;
    int cp = (l & 15) + 16 * h;
    int kbase = t * 32 + ((l >> 4) << 3);
    unsigned int pk[4];
#pragma unroll
    for (int q = 0; q < 4; ++q) {
        unsigned int a = 0, b = 0;
        int kd0 = kbase + 2 * q, kd1 = kd0 + 1;
        if (kd0 < kdact) { int c = kd0 / K, k = kd0 % K; a = f2bf(W[((size_t)k * cin + c) * C1 + cp]); }
        if (kd1 < kdact) { int c = kd1 / K, k = kd1 % K; b = f2bf(W[((size_t)k * cin + c) * C1 + cp]); }
        pk[q] = a | (b << 16);
    }
    uint4 u; u.x = pk[0]; u.y = pk[1]; u.z = pk[2]; u.w = pk[3];
    *(uint4*)(out + (size_t)li * 8) = u;
}

__global__ __launch_bounds__(256)
void wconv_all_kernel(const float* __restrict__ W1, const float* __restrict__ W2,
                      const float* __restrict__ W3,
                      unsigned short* __restrict__ Bfrg1,
                      unsigned short* __restrict__ Bfrag2,
                      unsigned short* __restrict__ Bfrag3) {
    int i = blockIdx.x * 256 + threadIdx.x;
    if (i < 1920)        wconv_entry(W2, Bfrag2, i, KD, CC);
    else if (i < 3840)   wconv_entry(W3, Bfrag3, i - 1920, KD, CC);
    else if (i < 3968)   wconv_entry(W1, Bfrg1, i - 3840, K, 1);
}

// ---------------- layer-1 gather: wave per node, 32-edge chunks ----------------
__global__ __launch_bounds__(256)
void gather1_kernel(const float* __restrict__ x, const unsigned short* __restrict__ ea_t,
                    const int* __restrict__ src_d, const int* __restrict__ rowptr,
                    unsigned short* __restrict__ Hb, int N, int E, int Epad) {
    int n = blockIdx.x * 4 + (int)(threadIdx.x >> 6);
    if (n >= N) return;                     // wave-uniform (one node per wave)
    int l = threadIdx.x & 63;
    int k = l & 15, g = l >> 4;
    int lo = rowptr[n], hi = (n + 1 < N) ? rowptr[n + 1] : E;
    float h = 0.f;
    for (int base = (lo & ~31); base < hi; base += 32) {
        float xs = 0.f;
        int e = base + l;
        if (l < 32 && e >= lo && e < hi) xs = x[src_d[e]];
        bf16x8 av = {0, 0, 0, 0, 0, 0, 0, 0};
        if (k < K) av = *(const bf16x8*)(ea_t + (size_t)k * Epad + base + g * 8);
        float p = 0.f;
#pragma unroll
        for (int j = 0; j < 8; ++j) {
            float xv = __shfl(xs, g * 8 + j);   // ALL 64 lanes active here
            p = fmaf(bf2f((unsigned short)av[j]), xv, p);
        }
        h += p;
    }
    h += __shfl_xor(h, 16);
    h += __shfl_xor(h, 32);
    if (l < 32) Hb[(size_t)n * 32 + l] = (l < K) ? f2bf(h) : (unsigned short)0;
}

// ---------------- layers 2/3: FUSED H-agg + hgemm + epilogue ----------------
template<bool FINAL>
__global__ __launch_bounds__(256)
void fusedM_kernel(const unsigned short* __restrict__ xb,
                   const float* __restrict__ xin,
                   const unsigned short* __restrict__ ea_t,
                   const int* __restrict__ src_d, const int* __restrict__ rowptr,
                   const unsigned short* __restrict__ Bfrag,
                   const float* __restrict__ bias,
                   const float* __restrict__ U, const float* __restrict__ ub,
                   const float* __restrict__ V, const float* __restrict__ vb,
                   float* __restrict__ xnext, unsigned short* __restrict__ xbnext,
                   const float* __restrict__ fc2w, const float* __restrict__ fc2b,
                   float* __restrict__ out, int N, int E, int Epad) {
    __shared__ unsigned short Hs[16][HROW];
    __shared__ float UVs[2][CC][C2];
    __shared__ float partial[3][16];
    int node0 = blockIdx.x * 16;
    if (node0 >= N) return;
    int t = threadIdx.x;
    int w = t >> 6, l = t & 63;
    // coop-load U,V (consumed by wave 2 only after the barrier)
    for (int i = t; i < CC * C2; i += 256) {
        UVs[0][i >> 4][i & 15] = U[i];
        UVs[1][i >> 4][i & 15] = V[i];
    }
    int row = l & 15;
    int eoff = (l >> 4) * 8;
    const unsigned short* aplane = ea_t + (size_t)row * Epad;
#pragma unroll
    for (int q = 0; q < 4; ++q) {
        int hrow = w * 4 + q;
        int n = node0 + hrow;
        f32x4 d0 = {0.f,0.f,0.f,0.f}, d1 = {0.f,0.f,0.f,0.f}, d2 = {0.f,0.f,0.f,0.f};
        if (n < N) {
            int lo = rowptr[n], hi = (n + 1 < N) ? rowptr[n + 1] : E;
            for (int base = (lo & ~31); base < hi; base += 32) {
                int e0 = base + eoff;
                uintx4 afu = {0u, 0u, 0u, 0u};
                if (row < K) afu = *(const uintx4*)(aplane + e0);    // 16B aligned
                int4 sA = *(const int4*)(src_d + e0);                // 32B aligned
                int4 sB = *(const int4*)(src_d + e0 + 4);
                int s0 = sA.x, s1 = sA.y, s2 = sA.z, s3 = sA.w;
                int s4 = sB.x, s5 = sB.y, s6 = sB.z, s7 = sB.w;
                bool v0,v1,v2,v3,v4,v5,v6,v7;
#define VCK(r, sv, vv) { int e = e0 + r; vv = (e >= lo) && (e < hi); sv = vv ? sv : 0; }
                VCK(0,s0,v0) VCK(1,s1,v1) VCK(2,s2,v2) VCK(3,s3,v3)
                VCK(4,s4,v4) VCK(5,s5,v5) VCK(6,s6,v6) VCK(7,s7,v7)
#undef VCK
                afu[0] &= (v0 ? 0x0000ffffu : 0u) | (v1 ? 0xffff0000u : 0u);
                afu[1] &= (v2 ? 0x0000ffffu : 0u) | (v3 ? 0xffff0000u : 0u);
                afu[2] &= (v4 ? 0x0000ffffu : 0u) | (v5 ? 0xffff0000u : 0u);
                afu[3] &= (v6 ? 0x0000ffffu : 0u) | (v7 ? 0xffff0000u : 0u);
                bf16x8 af = __builtin_bit_cast(bf16x8, afu);
                unsigned int bw0[4], bw1[4], bw2[4];
#define GPAIR(q2, sa, sb) { \
                const unsigned short* pa = xb + (size_t)sa * CC + row; \
                const unsigned short* pb = xb + (size_t)sb * CC + row; \
                bw0[q2] = (unsigned int)pa[0]  | ((unsigned int)pb[0]  << 16); \
                bw1[q2] = (unsigned int)pa[16] | ((unsigned int)pb[16] << 16); \
                bw2[q2] = (unsigned int)pa[32] | ((unsigned int)pb[32] << 16); }
                GPAIR(0, s0, s1)
                GPAIR(1, s2, s3)
                GPAIR(2, s4, s5)
                GPAIR(3, s6, s7)
#undef GPAIR
                uintx4 u0 = {bw0[0], bw0[1], bw0[2], bw0[3]};
                uintx4 u1 = {bw1[0], bw1[1], bw1[2], bw1[3]};
                uintx4 u2 = {bw2[0], bw2[1], bw2[2], bw2[3]};
                d0 = __builtin_amdgcn_mfma_f32_16x16x32_bf16(af, __builtin_bit_cast(bf16x8, u0), d0, 0, 0, 0);
                d1 = __builtin_amdgcn_mfma_f32_16x16x32_bf16(af, __builtin_bit_cast(bf16x8, u1), d1, 0, 0, 0);
                d2 = __builtin_amdgcn_mfma_f32_16x16x32_bf16(af, __builtin_bit_cast(bf16x8, u2), d2, 0, 0, 0);
            }
        }
        // store H row (kd = c*10 + k) into LDS; zeros for n>=N
        int rb = (l >> 4) * 4;
        if (rb < K) {
#define STORE_CG(dv, cg) { \
            int off = ((cg) * 16 + row) * K + rb; \
            *(unsigned int*)(&Hs[hrow][off]) = (unsigned int)f2bf(dv[0]) | ((unsigned int)f2bf(dv[1]) << 16); \
            if (rb != 8) \
                *(unsigned int*)(&Hs[hrow][off + 2]) = (unsigned int)f2bf(dv[2]) | ((unsigned int)f2bf(dv[3]) << 16); }
            STORE_CG(d0, 0) STORE_CG(d1, 1) STORE_CG(d2, 2)
#undef STORE_CG
        }
    }
    __syncthreads();
    // phase 2: waves 0/1 = hgemm + relu-epilogue; wave 2 = gate branch
    if (w < 2) {
        int koff2 = (l >> 4) * 8;
        f32x4 a = {0.f, 0.f, 0.f, 0.f};
#pragma unroll
        for (int ts = 0; ts < KSTEPS; ++ts) {
            bf16x8 af = *(const bf16x8*)(&Hs[row][ts * 32 + koff2]);
            bf16x8 b  = *(const bf16x8*)(Bfrag + (size_t)(ts * 2 + w) * 512 + l * 8);
            a = __builtin_amdgcn_mfma_f32_16x16x32_bf16(af, b, a, 0, 0, 0);
        }
        int col = l & 15, rbase = (l >> 4) * 4;
        float bval = bias[w * 16 + col];
        float wgt = FINAL ? fc2w[w * 16 + col] : 0.f;
#pragma unroll
        for (int r = 0; r < 4; ++r) {
            int node = node0 + rbase + r;
            float v = a[r] + bval;
            v = v > 0.f ? v : 0.f;
            if (!FINAL) {
                if (node < N) {
                    xnext[(size_t)node * CC + w * 16 + col] = v;
                    xbnext[(size_t)node * CC + w * 16 + col] = f2bf(v);
                }
            } else {
                float dp = v * wgt;
#pragma unroll
                for (int off = 8; off; off >>= 1) dp += __shfl_xor(dp, off, 16);
                if (col == 0) partial[w][rbase + r] = dp;
            }
        }
    } else if (w == 2) {
        int cp = l & 15, g2 = l >> 4;
        float wgt = FINAL ? fc2w[32 + cp] : 0.f;
        float ubv = ub[cp], vbv = vb[cp];
#pragma unroll
        for (int r = 0; r < 4; ++r) {
            int node = node0 + g2 * 4 + r;
            if (node < N) {
                float u = ubv, v = vbv;
                const float* xr = xin + (size_t)node * CC;
                for (int c = 0; c < CC; ++c) {
                    float xc = xr[c];
                    u = fmaf(xc, UVs[0][c][cp], u);
                    v = fmaf(xc, UVs[1][c][cp], v);
                }
                float g = u * v;
                if (!FINAL) {
                    xnext[(size_t)node * CC + 32 + cp] = g;
                    xbnext[(size_t)node * CC + 32 + cp] = f2bf(g);
                } else {
                    float dp = g * wgt;
#pragma unroll
                    for (int off = 8; off; off >>= 1) dp += __shfl_xor(dp, off, 16);
                    if (cp == 0) partial[2][g2 * 4 + r] = dp;
                }
            }
        }
    }
    if (FINAL) {
        __syncthreads();
        if (t < 16) {
            int node = node0 + t;
            if (node < N)
                out[node] = partial[0][t] + partial[1][t] + partial[2][t] + fc2b[0];
        }
    }
}

// ---------------- MFMA GEMM (layer 1 only): acc = Hb @ Bfrg1 ----------------
template<int KS>
__global__ __launch_bounds__(256)
void hgemm_kernel(const unsigned short* __restrict__ Hb,
                  const unsigned short* __restrict__ Bfrag,
                  float* __restrict__ acc, int N) {
    __shared__ unsigned short Bl[KS * 2 * 64 * 8];
    for (int i = threadIdx.x; i < KS * 2 * 64 * 4; i += 256)
        ((unsigned int*)Bl)[i] = ((const unsigned int*)Bfrag)[i];
    __syncthreads();
    int tile = blockIdx.x * 4 + (int)(threadIdx.x >> 6);
    int l = threadIdx.x & 63;
    int node0 = tile * 16;
    if (node0 >= N) return;
    constexpr int KDl = KS * 32;
    int row = l & 15, koff = (l >> 4) * 8;
    f32x4 a0 = {0.f,0.f,0.f,0.f}, a1 = {0.f,0.f,0.f,0.f};
#pragma unroll
    for (int t = 0; t < KS; ++t) {
        bf16x8 af = *(const bf16x8*)(Hb + (size_t)(node0 + row) * KDl + t * 32 + koff);
        bf16x8 b0 = *(const bf16x8*)(&Bl[(t * 2 + 0) * 64 * 8 + l * 8]);
        bf16x8 b1 = *(const bf16x8*)(&Bl[(t * 2 + 1) * 64 * 8 + l * 8]);
        a0 = __builtin_amdgcn_mfma_f32_16x16x32_bf16(af, b0, a0, 0, 0, 0);
        a1 = __builtin_amdgcn_mfma_f32_16x16x32_bf16(af, b1, a1, 0, 0, 0);
    }
    int col = l & 15, rbase = (l >> 4) * 4;
#pragma unroll
    for (int r = 0; r < 4; ++r) {
        int node = node0 + rbase + r;
        acc[(size_t)node * C1 + col]      = a0[r];
        acc[(size_t)node * C1 + 16 + col] = a1[r];
    }
}

// ---------------- node epilogue (layer 1 only) ----------------
template<int CIN, bool FINAL>
__global__ __launch_bounds__(256)
void epilogue_kernel(const float* __restrict__ acc, const float* __restrict__ b,
                     const float* __restrict__ x, const float* __restrict__ U,
                     const float* __restrict__ ub, const float* __restrict__ V,
                     const float* __restrict__ vb, float* __restrict__ xnext,
                     unsigned short* __restrict__ xbnext,
                     const float* __restrict__ fc2w, const float* __restrict__ fc2b,
                     float* __restrict__ out, int N) {
    int node = blockIdx.x * 16 + (int)(threadIdx.x >> 4);
    int cp   = threadIdx.x & 15;
    if (node >= N) return;
    float r0 = acc[(size_t)node * C1 + cp]      + b[cp];
    float r1 = acc[(size_t)node * C1 + 16 + cp] + b[16 + cp];
    r0 = r0 > 0.f ? r0 : 0.f;
    r1 = r1 > 0.f ? r1 : 0.f;
    float u = ub[cp], v = vb[cp];
#pragma unroll
    for (int c = 0; c < CIN; ++c) {
        float xc = x[(size_t)node * CIN + c];
        u = fmaf(xc, U[c * C2 + cp], u);
        v = fmaf(xc, V[c * C2 + cp], v);
    }
    float g = u * v;
    if (!FINAL) {
        xnext[(size_t)node * CC + cp]      = r0;
        xnext[(size_t)node * CC + 16 + cp] = r1;
        xnext[(size_t)node * CC + 32 + cp] = g;
        xbnext[(size_t)node * CC + cp]      = f2bf(r0);
        xbnext[(size_t)node * CC + 16 + cp] = f2bf(r1);
        xbnext[(size_t)node * CC + 32 + cp] = f2bf(g);
    } else {
        float dp = r0 * fc2w[cp] + r1 * fc2w[16 + cp] + g * fc2w[32 + cp];
#pragma unroll
        for (int off = 8; off; off >>= 1) dp += __shfl_xor(dp, off, 16);
        if (cp == 0) out[node] = dp + fc2b[0];
    }
}

// ---------------- fallback (atomic path) ----------------
__global__ __launch_bounds__(256)
void edge1_kernel(const float* __restrict__ x, const float* __restrict__ W1,
                  const float* __restrict__ ea, const int* __restrict__ src,
                  const int* __restrict__ dst, float* __restrict__ acc, int E) {
    __shared__ float Ws[K * C1];
    for (int i = threadIdx.x; i < K * C1; i += 256) Ws[i] = W1[i];
    __syncthreads();
    int gid = blockIdx.x * 256 + threadIdx.x;
    int e = gid >> 5;
    if (e >= E) return;
    int cp = threadIdx.x & 31;
    float xv = x[src[e]];
    const float* eap = ea + (size_t)e * K;
    float m = 0.f;
#pragma unroll
    for (int k = 0; k < K; ++k) m = fmaf(eap[k], Ws[k * C1 + cp], m);
    atomicAdd(acc + (size_t)dst[e] * C1 + cp, m * xv);
}

template<int CIN>
__global__ __launch_bounds__(256)
void xw_kernel(const float* __restrict__ x, const float* __restrict__ W,
               float* __restrict__ XW, int N) {
    __shared__ float Ws[K * CIN * C1];
    for (int i = threadIdx.x; i < K * CIN * C1; i += 256) Ws[i] = W[i];
    __syncthreads();
    int node = blockIdx.x * 8 + (int)(threadIdx.x >> 5);
    int cp = threadIdx.x & 31;
    if (node >= N) return;
    float xv[CIN];
#pragma unroll
    for (int c = 0; c < CIN; ++c) xv[c] = x[(size_t)node * CIN + c];
#pragma unroll
    for (int k = 0; k < K; ++k) {
        float a = 0.f;
#pragma unroll
        for (int c = 0; c < CIN; ++c) a = fmaf(xv[c], Ws[(k * CIN + c) * C1 + cp], a);
        XW[(size_t)node * (K * C1) + k * C1 + cp] = a;
    }
}

__global__ __launch_bounds__(256)
void edge_kernel(const float* __restrict__ XW, const float* __restrict__ ea,
                 const int* __restrict__ src, const int* __restrict__ dst,
                 float* __restrict__ acc, int E) {
    int gid = blockIdx.x * 256 + threadIdx.x;
    int e = gid >> 5;
    if (e >= E) return;
    int cp = threadIdx.x & 31;
    const float* xw = XW + (size_t)src[e] * (K * C1) + cp;
    const float* eap = ea + (size_t)e * K;
    float m = 0.f;
#pragma unroll
    for (int k = 0; k < K; ++k) m = fmaf(eap[k], xw[k * C1], m);
    atomicAdd(acc + (size_t)dst[e] * C1 + cp, m);
}

extern "C" void kernel_launch(void* const* d_in, const int* in_sizes, int n_in,
                              void* d_out, int out_size, void* d_ws, size_t ws_size,
                              hipStream_t stream) {
    const float* x  = (const float*)d_in[0];
    const float* ea = (const float*)d_in[1];
    const int*   ei = (const int*)d_in[2];
    const int N = in_sizes[0];      // NIN == 1
    const int E = in_sizes[1] / K;
    const int Epad = ((E + 31) & ~31) + 32;
    const int NB = (E + RTILE - 1) / RTILE;
    const int* srcp = ei;
    const int* dstp = ei + E;

    const float *W1 = (const float*)d_in[3],  *b1 = (const float*)d_in[4];
    const float *U1 = (const float*)d_in[5],  *ub1 = (const float*)d_in[6];
    const float *V1 = (const float*)d_in[7],  *vb1 = (const float*)d_in[8];
    const float *W2 = (const float*)d_in[9],  *b2 = (const float*)d_in[10];
    const float *U2 = (const float*)d_in[11], *ub2 = (const float*)d_in[12];
    const float *V2 = (const float*)d_in[13], *vb2 = (const float*)d_in[14];
    const float *W3 = (const float*)d_in[15], *b3 = (const float*)d_in[16];
    const float *U3 = (const float*)d_in[17], *ub3 = (const float*)d_in[18];
    const float *V3 = (const float*)d_in[19], *vb3 = (const float*)d_in[20];
    const float *fc2w = (const float*)d_in[21], *fc2b = (const float*)d_in[22];

    // ---- workspace layout ----
    // rec region (51.2 MB) is dead after materialize; x2/x3/xb2/xb3 overlay it.
    unsigned short* rec   = (unsigned short*)d_ws;           // E*16 u16   (51.2 MB)
    unsigned short* keys0 = rec + (size_t)E * 16;            // Epad u16   (3.2 MB)
    unsigned int*   idx0  = (unsigned int*)(keys0 + Epad);   // Epad u32   (6.4 MB)
    unsigned short* keys1 = (unsigned short*)(idx0 + Epad);  // Epad u16
    unsigned int*   idx1  = (unsigned int*)(keys1 + Epad);   // Epad u32
    unsigned int*   counts = idx1 + Epad;                    // 256*NB
    unsigned int*   gscan  = counts + (size_t)256 * NB;      // 256*NB
    unsigned int*   dtot   = gscan + (size_t)256 * NB;       // 256
    unsigned short* ea_t   = (unsigned short*)(dtot + 256);  // 10*Epad (32 MB)
    int* src_d  = (int*)(ea_t + (size_t)K * Epad);           // Epad      (6.4 MB)
    int* rowptr = src_d + Epad;                              // N
    float* acc  = (float*)(rowptr + N);                      // N*32 f32  (6.4 MB)
    unsigned short* Hb     = (unsigned short*)(acc + (size_t)N * C1); // N*480 (layer1 uses N*32)
    unsigned short* Bfrg1  = Hb + (size_t)N * KD;            // 1024
    unsigned short* Bfrag2 = Bfrg1 + 2 * 64 * 8;             // 15*1024
    unsigned short* Bfrag3 = Bfrag2 + KSTEPS * 2 * 64 * 8;   // 15*1024
    size_t needMain = (size_t)((char*)(Bfrag3 + KSTEPS * 2 * 64 * 8) - (char*)d_ws);
    // overlays (valid only after materialize)
    float* x2 = (float*)rec;
    float* x3 = x2 + (size_t)N * CC;
    unsigned short* xb2 = (unsigned short*)(x3 + (size_t)N * CC);
    unsigned short* xb3 = xb2 + (size_t)N * CC;
    bool mainPath = (ws_size >= needMain) && (N <= 65536) &&
                    ((size_t)N * CC * 4 * 2 + (size_t)N * CC * 2 * 2 <= (size_t)E * 16 * 2);

    const int eBlocks  = (E + 255) / 256;
    const int epadBlk  = (Epad + 255) / 256;
    const int nwBlocks = (N + 3) / 4;
    const int tiles    = (N + 15) / 16;
    const int gmBlocks = (tiles + 3) / 4;
    const int epBlocks = (N + 15) / 16;

    if (mainPath) {
        // ---- radix sort by dst (2x8-bit LSD, zero global atomics) ----
        build_kernel<<<eBlocks, 256, 0, stream>>>(ea, srcp, dstp, rec, keys0, idx0, E);
        rcount_kernel<0><<<NB, 256, 0, stream>>>(keys0, counts, E, NB);
        digit_scan_kernel<<<256, 256, 0, stream>>>(counts, gscan, dtot, NB);
        rscatter_kernel<0><<<NB, RS_THREADS, 0, stream>>>(keys0, idx0, gscan, dtot, keys1, idx1, E, NB);
        rcount_kernel<8><<<NB, 256, 0, stream>>>(keys1, counts, E, NB);
        digit_scan_kernel<<<256, 256, 0, stream>>>(counts, gscan, dtot, NB);
        rscatter_kernel<8><<<NB, RS_THREADS, 0, stream>>>(keys1, idx1, gscan, dtot, keys0, idx0, E, NB);
        materialize_kernel<<<epadBlk, 256, 0, stream>>>(idx0, rec, ea_t, src_d, E, Epad);
        rowptr_kernel<<<(N + 255) / 256, 256, 0, stream>>>(keys0, rowptr, N, E);
        wconv_all_kernel<<<16, 256, 0, stream>>>(W1, W2, W3, Bfrg1, Bfrag2, Bfrag3);

        // ---- layer 1 ----
        gather1_kernel<<<nwBlocks, 256, 0, stream>>>(x, ea_t, src_d, rowptr, Hb, N, E, Epad);
        hgemm_kernel<1><<<gmBlocks, 256, 0, stream>>>(Hb, Bfrg1, acc, N);
        epilogue_kernel<1, false><<<epBlocks, 256, 0, stream>>>(
            acc, b1, x, U1, ub1, V1, vb1, x2, xb2, nullptr, nullptr, nullptr, N);

        // ---- layer 2 (fused gatherM + hgemm + epilogue) ----
        fusedM_kernel<false><<<tiles, 256, 0, stream>>>(
            xb2, x2, ea_t, src_d, rowptr, Bfrag2, b2, U2, ub2, V2, vb2,
            x3, xb3, nullptr, nullptr, nullptr, N, E, Epad);

        // ---- layer 3 (fused gatherM + hgemm + fc2 epilogue) ----
        fusedM_kernel<true><<<tiles, 256, 0, stream>>>(
            xb3, x3, ea_t, src_d, rowptr, Bfrag3, b3, U3, ub3, V3, vb3,
            nullptr, nullptr, fc2w, fc2b, (float*)d_out, N, E, Epad);
    } else {
        // ---- fallback: unsorted atomic path (layout independent of main) ----
        float* accF = (float*)d_ws;
        float* x2F  = accF + (size_t)N * C1;
        float* x3F  = x2F + (size_t)N * CC;
        unsigned short* xb2F = (unsigned short*)(x3F + (size_t)N * CC);
        unsigned short* xb3F = xb2F + (size_t)N * CC;
        float* XW = (float*)(xb3F + (size_t)N * CC);
        const int egBlocks = (int)(((size_t)E * 32 + 255) / 256);
        const int xwBlocks = (N + 7) / 8;
        const size_t accBytes = (size_t)N * C1 * sizeof(float);

        hipMemsetAsync(accF, 0, accBytes, stream);
        edge1_kernel<<<egBlocks, 256, 0, stream>>>(x, W1, ea, srcp, dstp, accF, E);
        epilogue_kernel<1, false><<<epBlocks, 256, 0, stream>>>(
            accF, b1, x, U1, ub1, V1, vb1, x2F, xb2F, nullptr, nullptr, nullptr, N);

        hipMemsetAsync(accF, 0, accBytes, stream);
        xw_kernel<CC><<<xwBlocks, 256, 0, stream>>>(x2F, W2, XW, N);
        edge_kernel<<<egBlocks, 256, 0, stream>>>(XW, ea, srcp, dstp, accF, E);
        epilogue_kernel<CC, false><<<epBlocks, 256, 0, stream>>>(
            accF, b2, x2F, U2, ub2, V2, vb2, x3F, xb3F, nullptr, nullptr, nullptr, N);

        hipMemsetAsync(accF, 0, accBytes, stream);
        xw_kernel<CC><<<xwBlocks, 256, 0, stream>>>(x3F, W3, XW, N);
        edge_kernel<<<egBlocks, 256, 0, stream>>>(XW, ea, srcp, dstp, accF, E);
        epilogue_kernel<CC, true><<<epBlocks, 256, 0, stream>>>(
            accF, b3, x3F, U3, ub3, V3, vb3, nullptr, nullptr, fc2w, fc2b, (float*)d_out, N);
    }
}

// Round 25
// 286.643 us; speedup vs baseline: 1.0541x; 1.0541x over previous
//
#include <hip/hip_runtime.h>

// GNNML3 R25 (= R23 reverted, session best 287.1us): R24's epilogue fusion
// raised fusedM VGPR 44->68, occupancy 41->29%, +15us net -- reverted.
// Pipeline: atomic-free radix sort by dst (2x8-bit LSD, wave-ballot stable
// rank) -> bf16 ea_t planes + src_d -> MFMA H-aggregation fused with the
// [Nx480]@[480x32] weight GEMM via LDS (fusedM) -> separate epilogues.

constexpr int K  = 10;   // spectral supports
constexpr int C1 = 32;   // conv out
constexpr int C2 = 16;   // gate out
constexpr int CC = 48;   // concat width
constexpr int KD = 480;  // kd = c*10 + k
constexpr int KSTEPS = 15;
constexpr int HROW = 488;              // LDS H row stride (padded, bank-friendly)
constexpr int RTILE = 4096;            // radix items per block
constexpr int RS_WAVES  = 16;          // waves per rscatter block (1024 thr)
constexpr int RS_THREADS = RS_WAVES * 64;
constexpr int RS_ROUNDS = RTILE / RS_THREADS;        // 4 rounds per wave

typedef short bf16x8 __attribute__((ext_vector_type(8)));
typedef float f32x4  __attribute__((ext_vector_type(4)));
typedef unsigned int uintx4 __attribute__((ext_vector_type(4)));

static __device__ __forceinline__ unsigned short f2bf(float f) {
    unsigned int u = __float_as_uint(f);
    return (unsigned short)((u + 0x7FFFu + ((u >> 16) & 1u)) >> 16);
}
static __device__ __forceinline__ float bf2f(unsigned short h) {
    return __uint_as_float(((unsigned int)h) << 16);
}
static __device__ __forceinline__ unsigned int pk2(float a, float b) {
    return (unsigned int)f2bf(a) | ((unsigned int)f2bf(b) << 16);
}

// ---------------- build: keys + idx + packed 32B records ----------------
__global__ __launch_bounds__(256)
void build_kernel(const float* __restrict__ ea, const int* __restrict__ src,
                  const int* __restrict__ dst, unsigned short* __restrict__ rec,
                  unsigned short* __restrict__ keys0, unsigned int* __restrict__ idx0,
                  int E) {
    int e = blockIdx.x * 256 + threadIdx.x;
    if (e >= E) return;
    keys0[e] = (unsigned short)dst[e];
    idx0[e] = (unsigned int)e;
    const float2* ep = (const float2*)(ea + (size_t)e * K);
    float2 a0 = ep[0], a1 = ep[1], a2 = ep[2], a3 = ep[3], a4 = ep[4];
    uint4 r0, r1;
    r0.x = pk2(a0.x, a0.y); r0.y = pk2(a1.x, a1.y);
    r0.z = pk2(a2.x, a2.y); r0.w = pk2(a3.x, a3.y);
    r1.x = pk2(a4.x, a4.y); r1.y = (unsigned int)src[e];
    r1.z = 0u; r1.w = 0u;
    uint4* rp = (uint4*)(rec + (size_t)e * 16);
    rp[0] = r0; rp[1] = r1;
}

// ---------------- radix machinery (no global atomics) ----------------
template<int SHIFT>
__global__ __launch_bounds__(256)
void rcount_kernel(const unsigned short* __restrict__ keys,
                   unsigned int* __restrict__ counts, int E, int NB) {
    __shared__ unsigned int h[256];
    h[threadIdx.x] = 0;
    __syncthreads();
    int end = min((blockIdx.x + 1) * RTILE, E);
    for (int i = blockIdx.x * RTILE + threadIdx.x; i < end; i += 256)
        atomicAdd(&h[(keys[i] >> SHIFT) & 255], 1);   // LDS atomic (cheap)
    __syncthreads();
    counts[(size_t)threadIdx.x * NB + blockIdx.x] = h[threadIdx.x];
}

// per-digit exclusive scan across NB blocks: grid = 256 blocks (one per digit)
__global__ __launch_bounds__(256)
void digit_scan_kernel(const unsigned int* __restrict__ counts,
                       unsigned int* __restrict__ gscan,
                       unsigned int* __restrict__ dtot, int NB) {
    __shared__ unsigned int s[256];
    int d = blockIdx.x, t = threadIdx.x;
    const unsigned int* row = counts + (size_t)d * NB;
    unsigned int* orow = gscan + (size_t)d * NB;
    unsigned int running = 0;
    for (int base = 0; base < NB; base += 256) {
        int i = base + t;
        unsigned int v = (i < NB) ? row[i] : 0u;
        s[t] = v;
        __syncthreads();
#pragma unroll
        for (int off = 1; off < 256; off <<= 1) {
            unsigned int a = (t >= off) ? s[t - off] : 0u;
            __syncthreads();
            s[t] += a;
            __syncthreads();
        }
        if (i < NB) orow[i] = running + s[t] - v;   // exclusive
        running += s[255];
        __syncthreads();
    }
    if (t == 0) dtot[d] = running;
}

// stable scatter via wave-ballot ranking. 1024 threads (16 waves), ~51KB LDS.
template<int SHIFT>
__global__ __launch_bounds__(RS_THREADS)
void rscatter_kernel(const unsigned short* __restrict__ keyIn,
                     const unsigned int* __restrict__ idxIn,
                     const unsigned int* __restrict__ gscan,
                     const unsigned int* __restrict__ dtot,
                     unsigned short* __restrict__ keyOut,
                     unsigned int* __restrict__ idxOut, int E, int NB) {
    __shared__ unsigned int hw[RS_WAVES][256];    // per-wave digit histogram
    __shared__ unsigned int wex[RS_WAVES][256];   // wave-exclusive per-digit prefix
    __shared__ unsigned int wrun[RS_WAVES][256];  // per-wave running counters
    __shared__ unsigned int dbt[256];
    __shared__ unsigned int gb[256];              // global base per digit
    int t = threadIdx.x, b = blockIdx.x;
    int w = t >> 6, lane = t & 63;
    {
        unsigned int* hwf = &hw[0][0];
        unsigned int* wrf = &wrun[0][0];
        for (int i = t; i < RS_WAVES * 256; i += RS_THREADS) { hwf[i] = 0; wrf[i] = 0; }
    }
    unsigned int dv = (t < 256) ? dtot[t] : 0u;
    if (t < 256) dbt[t] = dv;
    __syncthreads();
#pragma unroll
    for (int off = 1; off < 256; off <<= 1) {
        unsigned int a = (t >= off && t < 256) ? dbt[t - off] : 0u;
        __syncthreads();
        if (t < 256) dbt[t] += a;
        __syncthreads();
    }
    if (t < 256) gb[t] = (dbt[t] - dv) + gscan[(size_t)t * NB + b];
    // phase 1: load items (wave-major, round-major, lane-major) + wave hists
    int base = b * RTILE + w * (RTILE / RS_WAVES);
    unsigned short keys[RS_ROUNDS]; unsigned int idxs[RS_ROUNDS]; unsigned int dig[RS_ROUNDS];
#pragma unroll
    for (int r = 0; r < RS_ROUNDS; ++r) {
        int i = base + r * 64 + lane;
        if (i < E) {
            keys[r] = keyIn[i];
            idxs[r] = idxIn[i];
            dig[r] = (keys[r] >> SHIFT) & 255u;
            atomicAdd(&hw[w][dig[r]], 1u);
        } else dig[r] = 0xFFFFFFFFu;
    }
    __syncthreads();
    // phase 2: per-digit wave-exclusive prefix (thread t<256 owns digit t)
    if (t < 256) {
        unsigned int s = 0;
#pragma unroll
        for (int ww = 0; ww < RS_WAVES; ++ww) { wex[ww][t] = s; s += hw[ww][t]; }
    }
    __syncthreads();
    // phase 3: stable rank, rounds in order within wave
#pragma unroll
    for (int r = 0; r < RS_ROUNDS; ++r) {
        bool valid = dig[r] != 0xFFFFFFFFu;
        unsigned int d = valid ? dig[r] : 0u;
        unsigned long long mask = __ballot(valid);
#pragma unroll
        for (int bit = 0; bit < 8; ++bit) {
            unsigned long long bb = __ballot(valid && ((d >> bit) & 1u));
            mask &= ((d >> bit) & 1u) ? bb : ~bb;
        }
        unsigned int old = 0;
        if (valid) {
            int leader = __ffsll((long long)mask) - 1;
            if (lane == leader) {
                old = wrun[w][d];
                wrun[w][d] = old + (unsigned int)__popcll(mask);
            }
            old = __shfl(old, leader);
            unsigned int myrank = (unsigned int)__popcll(mask & ((1ull << lane) - 1ull));
            unsigned int pos = gb[d] + wex[w][d] + old + myrank;
            keyOut[pos] = keys[r];
            idxOut[pos] = idxs[r];
        }
    }
}

// permutation gather: one 32B-aligned record read per edge -> planes + src_d
__global__ __launch_bounds__(256)
void materialize_kernel(const unsigned int* __restrict__ idxS,
                        const unsigned short* __restrict__ rec,
                        unsigned short* __restrict__ ea_t,
                        int* __restrict__ src_d, int E, int Epad) {
    int r = blockIdx.x * 256 + threadIdx.x;
    if (r >= Epad) return;
    if (r < E) {
        unsigned int p = idxS[r];
        const uint4* rp = (const uint4*)(rec + (size_t)p * 16);
        uint4 r0 = rp[0], r1 = rp[1];
        src_d[r] = (int)r1.y;
        ea_t[(size_t)0 * Epad + r] = (unsigned short)r0.x;
        ea_t[(size_t)1 * Epad + r] = (unsigned short)(r0.x >> 16);
        ea_t[(size_t)2 * Epad + r] = (unsigned short)r0.y;
        ea_t[(size_t)3 * Epad + r] = (unsigned short)(r0.y >> 16);
        ea_t[(size_t)4 * Epad + r] = (unsigned short)r0.z;
        ea_t[(size_t)5 * Epad + r] = (unsigned short)(r0.z >> 16);
        ea_t[(size_t)6 * Epad + r] = (unsigned short)r0.w;
        ea_t[(size_t)7 * Epad + r] = (unsigned short)(r0.w >> 16);
        ea_t[(size_t)8 * Epad + r] = (unsigned short)r1.x;
        ea_t[(size_t)9 * Epad + r] = (unsigned short)(r1.x >> 16);
    } else {
        src_d[r] = 0;
#pragma unroll
        for (int k = 0; k < K; ++k) ea_t[(size_t)k * Epad + r] = 0;
    }
}

// rowptr[n] = lower_bound(sorted keys, n)
__global__ __launch_bounds__(256)
void rowptr_kernel(const unsigned short* __restrict__ keysS,
                   int* __restrict__ rowptr, int N, int E) {
    int n = blockIdx.x * 256 + threadIdx.x;
    if (n >= N) return;
    int lo = 0, hi = E;
    while (lo < hi) {
        int mid = (lo + hi) >> 1;
        if ((int)keysS[mid] < n) lo = mid + 1; else hi = mid;
    }
    rowptr[n] = lo;
}

// ---------------- W -> B-fragments (all three in one launch) ----------------
static __device__ __forceinline__
void wconv_entry(const float* __restrict__ W, unsigned short* __restrict__ out,
                 int li, int kdact, int cin) {
    int t = li >> 7, rem = li & 127, h = rem >> 6, l = rem & 63;
    int cp = (l & 15) + 16 * h;
    int kbase = t * 32 + ((l >> 4) << 3);
    unsigned int pk[4];
#pragma unroll
    for (int q = 0; q < 4; ++q) {
        unsigned int a = 0, b = 0;
        int kd0 = kbase + 2 * q, kd1 = kd0 + 1;
        if (kd0 < kdact) { int c = kd0 / K, k = kd0 % K; a = f2bf(W[((size_t)k * cin + c) * C1 + cp]); }
        if (kd1 < kdact) { int c = kd1 / K, k = kd1 % K; b = f2bf(W[((size_t)k * cin + c) * C1 + cp]); }
        pk[q] = a | (b << 16);
    }
    uint4 u; u.x = pk[0]; u.y = pk[1]; u.z = pk[2]; u.w = pk[3];
    *(uint4*)(out + (size_t)li * 8) = u;
}

__global__ __launch_bounds__(256)
void wconv_all_kernel(const float* __restrict__ W1, const float* __restrict__ W2,
                      const float* __restrict__ W3,
                      unsigned short* __restrict__ Bfrg1,
                      unsigned short* __restrict__ Bfrag2,
                      unsigned short* __restrict__ Bfrag3) {
    int i = blockIdx.x * 256 + threadIdx.x;
    if (i < 1920)        wconv_entry(W2, Bfrag2, i, KD, CC);
    else if (i < 3840)   wconv_entry(W3, Bfrag3, i - 1920, KD, CC);
    else if (i < 3968)   wconv_entry(W1, Bfrg1, i - 3840, K, 1);
}

// ---------------- layer-1 gather: wave per node, 32-edge chunks ----------------
__global__ __launch_bounds__(256)
void gather1_kernel(const float* __restrict__ x, const unsigned short* __restrict__ ea_t,
                    const int* __restrict__ src_d, const int* __restrict__ rowptr,
                    unsigned short* __restrict__ Hb, int N, int E, int Epad) {
    int n = blockIdx.x * 4 + (int)(threadIdx.x >> 6);
    if (n >= N) return;                     // wave-uniform (one node per wave)
    int l = threadIdx.x & 63;
    int k = l & 15, g = l >> 4;
    int lo = rowptr[n], hi = (n + 1 < N) ? rowptr[n + 1] : E;
    float h = 0.f;
    for (int base = (lo & ~31); base < hi; base += 32) {
        float xs = 0.f;
        int e = base + l;
        if (l < 32 && e >= lo && e < hi) xs = x[src_d[e]];
        bf16x8 av = {0, 0, 0, 0, 0, 0, 0, 0};
        if (k < K) av = *(const bf16x8*)(ea_t + (size_t)k * Epad + base + g * 8);
        float p = 0.f;
#pragma unroll
        for (int j = 0; j < 8; ++j) {
            float xv = __shfl(xs, g * 8 + j);   // ALL 64 lanes active here
            p = fmaf(bf2f((unsigned short)av[j]), xv, p);
        }
        h += p;
    }
    h += __shfl_xor(h, 16);
    h += __shfl_xor(h, 32);
    if (l < 32) Hb[(size_t)n * 32 + l] = (l < K) ? f2bf(h) : (unsigned short)0;
}

// ---------------- layers 2/3: FUSED H-aggregation + hgemm ----------------
__global__ __launch_bounds__(256)
void fusedM_kernel(const unsigned short* __restrict__ xb,
                   const unsigned short* __restrict__ ea_t,
                   const int* __restrict__ src_d, const int* __restrict__ rowptr,
                   const unsigned short* __restrict__ Bfrag,
                   float* __restrict__ acc, int N, int E, int Epad) {
    __shared__ unsigned short Hs[16][HROW];
    int node0 = blockIdx.x * 16;
    if (node0 >= N) return;
    int t = threadIdx.x;
    int w = t >> 6, l = t & 63;
    int row = l & 15;
    int eoff = (l >> 4) * 8;
    const unsigned short* aplane = ea_t + (size_t)row * Epad;
#pragma unroll
    for (int q = 0; q < 4; ++q) {
        int hrow = w * 4 + q;
        int n = node0 + hrow;
        f32x4 d0 = {0.f,0.f,0.f,0.f}, d1 = {0.f,0.f,0.f,0.f}, d2 = {0.f,0.f,0.f,0.f};
        if (n < N) {
            int lo = rowptr[n], hi = (n + 1 < N) ? rowptr[n + 1] : E;
            for (int base = (lo & ~31); base < hi; base += 32) {
                int e0 = base + eoff;
                uintx4 afu = {0u, 0u, 0u, 0u};
                if (row < K) afu = *(const uintx4*)(aplane + e0);    // 16B aligned
                int4 sA = *(const int4*)(src_d + e0);                // 32B aligned
                int4 sB = *(const int4*)(src_d + e0 + 4);
                int s0 = sA.x, s1 = sA.y, s2 = sA.z, s3 = sA.w;
                int s4 = sB.x, s5 = sB.y, s6 = sB.z, s7 = sB.w;
                bool v0,v1,v2,v3,v4,v5,v6,v7;
#define VCK(r, sv, vv) { int e = e0 + r; vv = (e >= lo) && (e < hi); sv = vv ? sv : 0; }
                VCK(0,s0,v0) VCK(1,s1,v1) VCK(2,s2,v2) VCK(3,s3,v3)
                VCK(4,s4,v4) VCK(5,s5,v5) VCK(6,s6,v6) VCK(7,s7,v7)
#undef VCK
                afu[0] &= (v0 ? 0x0000ffffu : 0u) | (v1 ? 0xffff0000u : 0u);
                afu[1] &= (v2 ? 0x0000ffffu : 0u) | (v3 ? 0xffff0000u : 0u);
                afu[2] &= (v4 ? 0x0000ffffu : 0u) | (v5 ? 0xffff0000u : 0u);
                afu[3] &= (v6 ? 0x0000ffffu : 0u) | (v7 ? 0xffff0000u : 0u);
                bf16x8 af = __builtin_bit_cast(bf16x8, afu);
                unsigned int bw0[4], bw1[4], bw2[4];
#define GPAIR(q2, sa, sb) { \
                const unsigned short* pa = xb + (size_t)sa * CC + row; \
                const unsigned short* pb = xb + (size_t)sb * CC + row; \
                bw0[q2] = (unsigned int)pa[0]  | ((unsigned int)pb[0]  << 16); \
                bw1[q2] = (unsigned int)pa[16] | ((unsigned int)pb[16] << 16); \
                bw2[q2] = (unsigned int)pa[32] | ((unsigned int)pb[32] << 16); }
                GPAIR(0, s0, s1)
                GPAIR(1, s2, s3)
                GPAIR(2, s4, s5)
                GPAIR(3, s6, s7)
#undef GPAIR
                uintx4 u0 = {bw0[0], bw0[1], bw0[2], bw0[3]};
                uintx4 u1 = {bw1[0], bw1[1], bw1[2], bw1[3]};
                uintx4 u2 = {bw2[0], bw2[1], bw2[2], bw2[3]};
                d0 = __builtin_amdgcn_mfma_f32_16x16x32_bf16(af, __builtin_bit_cast(bf16x8, u0), d0, 0, 0, 0);
                d1 = __builtin_amdgcn_mfma_f32_16x16x32_bf16(af, __builtin_bit_cast(bf16x8, u1), d1, 0, 0, 0);
                d2 = __builtin_amdgcn_mfma_f32_16x16x32_bf16(af, __builtin_bit_cast(bf16x8, u2), d2, 0, 0, 0);
            }
        }
        // store H row (kd = c*10 + k) into LDS; zeros for n>=N
        int rb = (l >> 4) * 4;
        if (rb < K) {
#define STORE_CG(dv, cg) { \
            int off = ((cg) * 16 + row) * K + rb; \
            *(unsigned int*)(&Hs[hrow][off]) = (unsigned int)f2bf(dv[0]) | ((unsigned int)f2bf(dv[1]) << 16); \
            if (rb != 8) \
                *(unsigned int*)(&Hs[hrow][off + 2]) = (unsigned int)f2bf(dv[2]) | ((unsigned int)f2bf(dv[3]) << 16); }
            STORE_CG(d0, 0) STORE_CG(d1, 1) STORE_CG(d2, 2)
#undef STORE_CG
        }
    }
    __syncthreads();
    // hgemm for the 16-node tile: wave 0 -> cols 0..15, wave 1 -> cols 16..31
    if (w < 2) {
        int koff2 = (l >> 4) * 8;
        f32x4 a = {0.f, 0.f, 0.f, 0.f};
#pragma unroll
        for (int ts = 0; ts < KSTEPS; ++ts) {
            bf16x8 af = *(const bf16x8*)(&Hs[row][ts * 32 + koff2]);
            bf16x8 b  = *(const bf16x8*)(Bfrag + (size_t)(ts * 2 + w) * 512 + l * 8);
            a = __builtin_amdgcn_mfma_f32_16x16x32_bf16(af, b, a, 0, 0, 0);
        }
        int col = l & 15, rbase = (l >> 4) * 4;
#pragma unroll
        for (int r = 0; r < 4; ++r) {
            int node = node0 + rbase + r;
            if (node < N) acc[(size_t)node * C1 + w * 16 + col] = a[r];
        }
    }
}

// ---------------- MFMA GEMM (layer 1 only): acc = Hb @ Bfrg1 ----------------
template<int KS>
__global__ __launch_bounds__(256)
void hgemm_kernel(const unsigned short* __restrict__ Hb,
                  const unsigned short* __restrict__ Bfrag,
                  float* __restrict__ acc, int N) {
    __shared__ unsigned short Bl[KS * 2 * 64 * 8];
    for (int i = threadIdx.x; i < KS * 2 * 64 * 4; i += 256)
        ((unsigned int*)Bl)[i] = ((const unsigned int*)Bfrag)[i];
    __syncthreads();
    int tile = blockIdx.x * 4 + (int)(threadIdx.x >> 6);
    int l = threadIdx.x & 63;
    int node0 = tile * 16;
    if (node0 >= N) return;
    constexpr int KDl = KS * 32;
    int row = l & 15, koff = (l >> 4) * 8;
    f32x4 a0 = {0.f,0.f,0.f,0.f}, a1 = {0.f,0.f,0.f,0.f};
#pragma unroll
    for (int t = 0; t < KS; ++t) {
        bf16x8 af = *(const bf16x8*)(Hb + (size_t)(node0 + row) * KDl + t * 32 + koff);
        bf16x8 b0 = *(const bf16x8*)(&Bl[(t * 2 + 0) * 64 * 8 + l * 8]);
        bf16x8 b1 = *(const bf16x8*)(&Bl[(t * 2 + 1) * 64 * 8 + l * 8]);
        a0 = __builtin_amdgcn_mfma_f32_16x16x32_bf16(af, b0, a0, 0, 0, 0);
        a1 = __builtin_amdgcn_mfma_f32_16x16x32_bf16(af, b1, a1, 0, 0, 0);
    }
    int col = l & 15, rbase = (l >> 4) * 4;
#pragma unroll
    for (int r = 0; r < 4; ++r) {
        int node = node0 + rbase + r;
        acc[(size_t)node * C1 + col]      = a0[r];
        acc[(size_t)node * C1 + 16 + col] = a1[r];
    }
}

// ---------------- node epilogue (emits f32 + bf16 xnext) ----------------
template<int CIN, bool FINAL>
__global__ __launch_bounds__(256)
void epilogue_kernel(const float* __restrict__ acc, const float* __restrict__ b,
                     const float* __restrict__ x, const float* __restrict__ U,
                     const float* __restrict__ ub, const float* __restrict__ V,
                     const float* __restrict__ vb, float* __restrict__ xnext,
                     unsigned short* __restrict__ xbnext,
                     const float* __restrict__ fc2w, const float* __restrict__ fc2b,
                     float* __restrict__ out, int N) {
    int node = blockIdx.x * 16 + (int)(threadIdx.x >> 4);
    int cp   = threadIdx.x & 15;
    if (node >= N) return;
    float r0 = acc[(size_t)node * C1 + cp]      + b[cp];
    float r1 = acc[(size_t)node * C1 + 16 + cp] + b[16 + cp];
    r0 = r0 > 0.f ? r0 : 0.f;
    r1 = r1 > 0.f ? r1 : 0.f;
    float u = ub[cp], v = vb[cp];
#pragma unroll
    for (int c = 0; c < CIN; ++c) {
        float xc = x[(size_t)node * CIN + c];
        u = fmaf(xc, U[c * C2 + cp], u);
        v = fmaf(xc, V[c * C2 + cp], v);
    }
    float g = u * v;
    if (!FINAL) {
        xnext[(size_t)node * CC + cp]      = r0;
        xnext[(size_t)node * CC + 16 + cp] = r1;
        xnext[(size_t)node * CC + 32 + cp] = g;
        xbnext[(size_t)node * CC + cp]      = f2bf(r0);
        xbnext[(size_t)node * CC + 16 + cp] = f2bf(r1);
        xbnext[(size_t)node * CC + 32 + cp] = f2bf(g);
    } else {
        float dp = r0 * fc2w[cp] + r1 * fc2w[16 + cp] + g * fc2w[32 + cp];
#pragma unroll
        for (int off = 8; off; off >>= 1) dp += __shfl_xor(dp, off, 16);
        if (cp == 0) out[node] = dp + fc2b[0];
    }
}

// ---------------- fallback (atomic path) ----------------
__global__ __launch_bounds__(256)
void edge1_kernel(const float* __restrict__ x, const float* __restrict__ W1,
                  const float* __restrict__ ea, const int* __restrict__ src,
                  const int* __restrict__ dst, float* __restrict__ acc, int E) {
    __shared__ float Ws[K * C1];
    for (int i = threadIdx.x; i < K * C1; i += 256) Ws[i] = W1[i];
    __syncthreads();
    int gid = blockIdx.x * 256 + threadIdx.x;
    int e = gid >> 5;
    if (e >= E) return;
    int cp = threadIdx.x & 31;
    float xv = x[src[e]];
    const float* eap = ea + (size_t)e * K;
    float m = 0.f;
#pragma unroll
    for (int k = 0; k < K; ++k) m = fmaf(eap[k], Ws[k * C1 + cp], m);
    atomicAdd(acc + (size_t)dst[e] * C1 + cp, m * xv);
}

template<int CIN>
__global__ __launch_bounds__(256)
void xw_kernel(const float* __restrict__ x, const float* __restrict__ W,
               float* __restrict__ XW, int N) {
    __shared__ float Ws[K * CIN * C1];
    for (int i = threadIdx.x; i < K * CIN * C1; i += 256) Ws[i] = W[i];
    __syncthreads();
    int node = blockIdx.x * 8 + (int)(threadIdx.x >> 5);
    int cp = threadIdx.x & 31;
    if (node >= N) return;
    float xv[CIN];
#pragma unroll
    for (int c = 0; c < CIN; ++c) xv[c] = x[(size_t)node * CIN + c];
#pragma unroll
    for (int k = 0; k < K; ++k) {
        float a = 0.f;
#pragma unroll
        for (int c = 0; c < CIN; ++c) a = fmaf(xv[c], Ws[(k * CIN + c) * C1 + cp], a);
        XW[(size_t)node * (K * C1) + k * C1 + cp] = a;
    }
}

__global__ __launch_bounds__(256)
void edge_kernel(const float* __restrict__ XW, const float* __restrict__ ea,
                 const int* __restrict__ src, const int* __restrict__ dst,
                 float* __restrict__ acc, int E) {
    int gid = blockIdx.x * 256 + threadIdx.x;
    int e = gid >> 5;
    if (e >= E) return;
    int cp = threadIdx.x & 31;
    const float* xw = XW + (size_t)src[e] * (K * C1) + cp;
    const float* eap = ea + (size_t)e * K;
    float m = 0.f;
#pragma unroll
    for (int k = 0; k < K; ++k) m = fmaf(eap[k], xw[k * C1], m);
    atomicAdd(acc + (size_t)dst[e] * C1 + cp, m);
}

extern "C" void kernel_launch(void* const* d_in, const int* in_sizes, int n_in,
                              void* d_out, int out_size, void* d_ws, size_t ws_size,
                              hipStream_t stream) {
    const float* x  = (const float*)d_in[0];
    const float* ea = (const float*)d_in[1];
    const int*   ei = (const int*)d_in[2];
    const int N = in_sizes[0];      // NIN == 1
    const int E = in_sizes[1] / K;
    const int Epad = ((E + 31) & ~31) + 32;
    const int NB = (E + RTILE - 1) / RTILE;
    const int* srcp = ei;
    const int* dstp = ei + E;

    const float *W1 = (const float*)d_in[3],  *b1 = (const float*)d_in[4];
    const float *U1 = (const float*)d_in[5],  *ub1 = (const float*)d_in[6];
    const float *V1 = (const float*)d_in[7],  *vb1 = (const float*)d_in[8];
    const float *W2 = (const float*)d_in[9],  *b2 = (const float*)d_in[10];
    const float *U2 = (const float*)d_in[11], *ub2 = (const float*)d_in[12];
    const float *V2 = (const float*)d_in[13], *vb2 = (const float*)d_in[14];
    const float *W3 = (const float*)d_in[15], *b3 = (const float*)d_in[16];
    const float *U3 = (const float*)d_in[17], *ub3 = (const float*)d_in[18];
    const float *V3 = (const float*)d_in[19], *vb3 = (const float*)d_in[20];
    const float *fc2w = (const float*)d_in[21], *fc2b = (const float*)d_in[22];

    // ---- workspace layout ----
    // rec region (51.2 MB) is dead after materialize; x2/x3/xb2/xb3 overlay it.
    unsigned short* rec   = (unsigned short*)d_ws;           // E*16 u16   (51.2 MB)
    unsigned short* keys0 = rec + (size_t)E * 16;            // Epad u16   (3.2 MB)
    unsigned int*   idx0  = (unsigned int*)(keys0 + Epad);   // Epad u32   (6.4 MB)
    unsigned short* keys1 = (unsigned short*)(idx0 + Epad);  // Epad u16
    unsigned int*   idx1  = (unsigned int*)(keys1 + Epad);   // Epad u32
    unsigned int*   counts = idx1 + Epad;                    // 256*NB
    unsigned int*   gscan  = counts + (size_t)256 * NB;      // 256*NB
    unsigned int*   dtot   = gscan + (size_t)256 * NB;       // 256
    unsigned short* ea_t   = (unsigned short*)(dtot + 256);  // 10*Epad (32 MB)
    int* src_d  = (int*)(ea_t + (size_t)K * Epad);           // Epad      (6.4 MB)
    int* rowptr = src_d + Epad;                              // N
    float* acc  = (float*)(rowptr + N);                      // N*32 f32  (6.4 MB)
    unsigned short* Hb     = (unsigned short*)(acc + (size_t)N * C1); // N*480 (layer1 uses N*32)
    unsigned short* Bfrg1  = Hb + (size_t)N * KD;            // 1024
    unsigned short* Bfrag2 = Bfrg1 + 2 * 64 * 8;             // 15*1024
    unsigned short* Bfrag3 = Bfrag2 + KSTEPS * 2 * 64 * 8;   // 15*1024
    size_t needMain = (size_t)((char*)(Bfrag3 + KSTEPS * 2 * 64 * 8) - (char*)d_ws);
    // overlays (valid only after materialize)
    float* x2 = (float*)rec;
    float* x3 = x2 + (size_t)N * CC;
    unsigned short* xb2 = (unsigned short*)(x3 + (size_t)N * CC);
    unsigned short* xb3 = xb2 + (size_t)N * CC;
    bool mainPath = (ws_size >= needMain) && (N <= 65536) &&
                    ((size_t)N * CC * 4 * 2 + (size_t)N * CC * 2 * 2 <= (size_t)E * 16 * 2);

    const int eBlocks  = (E + 255) / 256;
    const int epadBlk  = (Epad + 255) / 256;
    const int nwBlocks = (N + 3) / 4;
    const int tiles    = (N + 15) / 16;
    const int gmBlocks = (tiles + 3) / 4;
    const int epBlocks = (N + 15) / 16;

    if (mainPath) {
        // ---- radix sort by dst (2x8-bit LSD, zero global atomics) ----
        build_kernel<<<eBlocks, 256, 0, stream>>>(ea, srcp, dstp, rec, keys0, idx0, E);
        rcount_kernel<0><<<NB, 256, 0, stream>>>(keys0, counts, E, NB);
        digit_scan_kernel<<<256, 256, 0, stream>>>(counts, gscan, dtot, NB);
        rscatter_kernel<0><<<NB, RS_THREADS, 0, stream>>>(keys0, idx0, gscan, dtot, keys1, idx1, E, NB);
        rcount_kernel<8><<<NB, 256, 0, stream>>>(keys1, counts, E, NB);
        digit_scan_kernel<<<256, 256, 0, stream>>>(counts, gscan, dtot, NB);
        rscatter_kernel<8><<<NB, RS_THREADS, 0, stream>>>(keys1, idx1, gscan, dtot, keys0, idx0, E, NB);
        materialize_kernel<<<epadBlk, 256, 0, stream>>>(idx0, rec, ea_t, src_d, E, Epad);
        rowptr_kernel<<<(N + 255) / 256, 256, 0, stream>>>(keys0, rowptr, N, E);
        wconv_all_kernel<<<16, 256, 0, stream>>>(W1, W2, W3, Bfrg1, Bfrag2, Bfrag3);

        // ---- layer 1 ----
        gather1_kernel<<<nwBlocks, 256, 0, stream>>>(x, ea_t, src_d, rowptr, Hb, N, E, Epad);
        hgemm_kernel<1><<<gmBlocks, 256, 0, stream>>>(Hb, Bfrg1, acc, N);
        epilogue_kernel<1, false><<<epBlocks, 256, 0, stream>>>(
            acc, b1, x, U1, ub1, V1, vb1, x2, xb2, nullptr, nullptr, nullptr, N);

        // ---- layer 2 (fused gatherM + hgemm) ----
        fusedM_kernel<<<tiles, 256, 0, stream>>>(xb2, ea_t, src_d, rowptr, Bfrag2, acc, N, E, Epad);
        epilogue_kernel<CC, false><<<epBlocks, 256, 0, stream>>>(
            acc, b2, x2, U2, ub2, V2, vb2, x3, xb3, nullptr, nullptr, nullptr, N);

        // ---- layer 3 (fused gatherM + hgemm) ----
        fusedM_kernel<<<tiles, 256, 0, stream>>>(xb3, ea_t, src_d, rowptr, Bfrag3, acc, N, E, Epad);
        epilogue_kernel<CC, true><<<epBlocks, 256, 0, stream>>>(
            acc, b3, x3, U3, ub3, V3, vb3, nullptr, nullptr, fc2w, fc2b, (float*)d_out, N);
    } else {
        // ---- fallback: unsorted atomic path (layout independent of main) ----
        float* accF = (float*)d_ws;
        float* x2F  = accF + (size_t)N * C1;
        float* x3F  = x2F + (size_t)N * CC;
        unsigned short* xb2F = (unsigned short*)(x3F + (size_t)N * CC);
        unsigned short* xb3F = xb2F + (size_t)N * CC;
        float* XW = (float*)(xb3F + (size_t)N * CC);
        const int egBlocks = (int)(((size_t)E * 32 + 255) / 256);
        const int xwBlocks = (N + 7) / 8;
        const size_t accBytes = (size_t)N * C1 * sizeof(float);

        hipMemsetAsync(accF, 0, accBytes, stream);
        edge1_kernel<<<egBlocks, 256, 0, stream>>>(x, W1, ea, srcp, dstp, accF, E);
        epilogue_kernel<1, false><<<epBlocks, 256, 0, stream>>>(
            accF, b1, x, U1, ub1, V1, vb1, x2F, xb2F, nullptr, nullptr, nullptr, N);

        hipMemsetAsync(accF, 0, accBytes, stream);
        xw_kernel<CC><<<xwBlocks, 256, 0, stream>>>(x2F, W2, XW, N);
        edge_kernel<<<egBlocks, 256, 0, stream>>>(XW, ea, srcp, dstp, accF, E);
        epilogue_kernel<CC, false><<<epBlocks, 256, 0, stream>>>(
            accF, b2, x2F, U2, ub2, V2, vb2, x3F, xb3F, nullptr, nullptr, nullptr, N);

        hipMemsetAsync(accF, 0, accBytes, stream);
        xw_kernel<CC><<<xwBlocks, 256, 0, stream>>>(x3F, W3, XW, N);
        edge_kernel<<<egBlocks, 256, 0, stream>>>(XW, ea, srcp, dstp, accF, E);
        epilogue_kernel<CC, true><<<epBlocks, 256, 0, stream>>>(
            accF, b3, x3F, U3, ub3, V3, vb3, nullptr, nullptr, fc2w, fc2b, (float*)d_out, N);
    }
}